// Round 8
// baseline (3976.131 us; speedup 1.0000x reference)
//
#include <hip/hip_runtime.h>

// Problem constants
#define TT 20
#define NNODE 512
#define G2C 16
#define RCH 128
#define ECH 64
#define ICH 2
#define OCH 5
#define KSOC 8192          // N*G2
#define KSPLIT 32
#define KCH 256            // KSOC/KSPLIT
#define SGS 260            // f32 LDS row stride (260%8==4 -> staggered banks)
#define NBLK 1024
#define NLEAF 16

// workspace layout (double offsets)
#define OFF_H    0u         // h ping  [512*128]
#define OFF_C    65536u     // c       [512*128]
#define OFF_HT   131072u    // Ht      [8192][64]
#define OFF_PART 655360u    // part    [32][512][64]
#define OFF_WCAT 1703936u   // Wcat    [512 gc][256 kk]
#define OFF_WTT  1835008u   // WtT     [2048 q2][64 e]
#define OFF_BS   1966080u   // bs      [512 gc]
#define OFF_BAR  1966592u   // barrier: 2048 u32 (leaf@lg*32, root@512, gate@1024+lg*32)
#define OFF_H2   1967616u   // h pong  [512*128]
// total 2033152 doubles = 16.27 MB (ws is ~1.3 GB)

#define AT_LOADD(p)    __hip_atomic_load((p), __ATOMIC_RELAXED, __HIP_MEMORY_SCOPE_AGENT)
#define AT_STORED(p,v) __hip_atomic_store((p), (v), __ATOMIC_RELAXED, __HIP_MEMORY_SCOPE_AGENT)

__device__ __forceinline__ double sigd(double x){ return 1.0/(1.0+exp(-x)); }

__global__ void k_init(const float* __restrict__ h0, const float* __restrict__ c0,
                       const float* __restrict__ W_ih, const float* __restrict__ b_ih,
                       const float* __restrict__ W_hh, const float* __restrict__ b_hh,
                       const float* __restrict__ W_tensor, double* __restrict__ ws) {
  int tid = blockIdx.x*blockDim.x + threadIdx.x;
  int nthr = gridDim.x*blockDim.x;
  double* h = ws + OFF_H; double* c = ws + OFF_C;
  double* Wcat = ws + OFF_WCAT; double* WtT = ws + OFF_WTT;
  double* bs = ws + OFF_BS;
  if (tid < 2048) ((unsigned*)(ws + OFF_BAR))[tid] = 0u;
  for (int i = tid; i < NNODE*RCH; i += nthr) { h[i] = (double)h0[i]; c[i] = (double)c0[i]; }
  for (int i = tid; i < 512*256; i += nthr) {
    int kk = i & 255; int gc = i >> 8;
    Wcat[i] = (kk < 128) ? (double)W_ih[gc*128 + kk] : (double)W_hh[gc*128 + (kk-128)];
  }
  for (int i = tid; i < 2048*64; i += nthr) {
    int e = i & 63; int q2 = i >> 6;
    WtT[i] = (double)W_tensor[e*2048 + q2];
  }
  for (int i = tid; i < 512; i += nthr) bs[i] = (double)b_ih[i] + (double)b_hh[i];
}

// Fence-free grid barrier (see R7 notes). Leaf/root/gate words each on own line.
__device__ __forceinline__ void grid_sync(unsigned* bar, unsigned gen, int bid) {
  __syncthreads();
  if (threadIdx.x == 0) {
    __builtin_amdgcn_s_waitcnt(0);
    const int lg = bid & (NLEAF-1);
    unsigned prev = __hip_atomic_fetch_add(bar + (lg<<5), 1u, __ATOMIC_RELAXED,
                                           __HIP_MEMORY_SCOPE_AGENT);
    if (prev == (NBLK/NLEAF)-1u) {
      unsigned pr = __hip_atomic_fetch_add(bar+512, 1u, __ATOMIC_RELAXED,
                                           __HIP_MEMORY_SCOPE_AGENT);
      if (pr == NLEAF-1u) {
        #pragma unroll
        for (int i = 0; i < NLEAF; ++i)
          __hip_atomic_store(bar + (i<<5), 0u, __ATOMIC_RELAXED, __HIP_MEMORY_SCOPE_AGENT);
        __hip_atomic_store(bar+512, 0u, __ATOMIC_RELAXED, __HIP_MEMORY_SCOPE_AGENT);
        __builtin_amdgcn_s_waitcnt(0);   // resets visible before gates open
        #pragma unroll
        for (int i = 0; i < NLEAF; ++i)
          __hip_atomic_store(bar + 1024 + (i<<5), gen+1u, __ATOMIC_RELAXED,
                             __HIP_MEMORY_SCOPE_AGENT);
      }
    }
    unsigned* gate = bar + 1024 + (lg<<5);
    if (__hip_atomic_load(gate, __ATOMIC_RELAXED, __HIP_MEMORY_SCOPE_AGENT) != gen+1u) {
      do {
        __builtin_amdgcn_s_sleep(16);
      } while (__hip_atomic_load(gate, __ATOMIC_RELAXED,
                                 __HIP_MEMORY_SCOPE_AGENT) != gen+1u);
    }
    asm volatile("" ::: "memory");
  }
  __syncthreads();
}

__global__ __launch_bounds__(256, 4) void k_steps(
    const float* __restrict__ nodes, const float* __restrict__ grids,
    const float* __restrict__ W_in, const float* __restrict__ b_in,
    const float* __restrict__ b_tensor,
    const float* __restrict__ W_out, const float* __restrict__ b_out,
    double* __restrict__ ws, float* __restrict__ outp,
    float* __restrict__ hf, float* __restrict__ cf) {
  __shared__ __align__(16) double smem[3264];   // 26.1 KB
  double* __restrict__ c = ws + OFF_C;
  double* __restrict__ Ht = ws + OFF_HT;
  double* __restrict__ part = ws + OFF_PART;
  const double* __restrict__ Wcat = ws + OFF_WCAT;
  const double* __restrict__ WtT = ws + OFF_WTT;
  const double* __restrict__ bs = ws + OFF_BS;
  unsigned* bar = (unsigned*)(ws + OFF_BAR);
  const int tid = threadIdx.x;
  const int bid = blockIdx.x;
  unsigned gen = 0;

  // ---- phase HT(t=0): Ht from h(0) ----
  {
    double (*h2b)[130] = (double(*)[130])smem;
    const double* hsrc = ws + OFF_H;
    const int mc = bid >> 4, g = bid & 15;
    const int m0 = mc << 3;
    const int r = tid & 127;
    #pragma unroll
    for (int pass = 0; pass < 4; ++pass) {
      const int n = (tid >> 7) + (pass << 1);
      h2b[n][r] = AT_LOADD(hsrc + (size_t)(m0+n)*RCH + r);
    }
    __syncthreads();
    const int e = tid & 63, mh = tid >> 6;
    const double* wt = WtT + (size_t)(g*128)*ECH + e;
    double acc[2] = {};
    #pragma unroll 4
    for (int rr = 0; rr < 128; ++rr) {
      double w0 = wt[(size_t)rr*ECH];
      acc[0] += h2b[(mh<<1)][rr]*w0;
      acc[1] += h2b[(mh<<1)+1][rr]*w0;
    }
    #pragma unroll
    for (int mi = 0; mi < 2; ++mi)
      AT_STORED(Ht + ((size_t)(m0+(mh<<1)+mi)*G2C + g)*ECH + e, acc[mi]);
  }
  grid_sync(bar, gen, bid); ++gen;

  for (int t = 0; t < TT; ++t) {
    const double* hcur = ws + ((t & 1) ? OFF_H2 : OFF_H);
    double*       hnxt = ws + ((t & 1) ? OFF_H  : OFF_H2);

    // ---- phase SOCIAL: part[kc][n][e], 32 ng x 32 kc ----
    {
      float* sgf = (float*)smem;            // [16][260]
      const int kc = bid & 31;
      const int n0 = (bid >> 5) << 4;
      const int kb = kc * KCH;
      const float* gbase = grids + (size_t)t*NNODE*KSOC;
      for (int i = tid; i < 16*64; i += 256) {
        int row = i >> 6; int c4 = i & 63;
        float4 v = *(const float4*)(gbase + (size_t)(n0+row)*KSOC + kb + (c4<<2));
        *(float4*)(&sgf[row*SGS + (c4<<2)]) = v;
      }
      __syncthreads();
      const int lane = tid & 63;
      const int wv = tid >> 6;
      const int kl0 = wv << 6;              // 64 k per wave
      double acc[16];
      #pragma unroll
      for (int j = 0; j < 16; ++j) acc[j] = 0.0;
      const double* htp = Ht + (size_t)(kb + kl0)*ECH + lane;
      // 1-deep pipelined: coalesced sc1 loads (64 lanes x contiguous e)
      double b0 = AT_LOADD(htp + 0*ECH);
      double b1 = AT_LOADD(htp + 1*ECH);
      double b2 = AT_LOADD(htp + 2*ECH);
      double b3 = AT_LOADD(htp + 3*ECH);
      #pragma unroll
      for (int kg = 0; kg < 16; ++kg) {
        double n0d, n1d, n2d, n3d;
        if (kg < 15) {
          const double* np = htp + (size_t)((kg<<2)+4)*ECH;
          n0d = AT_LOADD(np + 0*ECH); n1d = AT_LOADD(np + 1*ECH);
          n2d = AT_LOADD(np + 2*ECH); n3d = AT_LOADD(np + 3*ECH);
        }
        const int kl = kl0 + (kg<<2);
        #pragma unroll
        for (int jn = 0; jn < 16; ++jn) {
          float4 g4 = *(const float4*)(&sgf[jn*SGS + kl]);   // LDS broadcast
          acc[jn] += (double)g4.x*b0 + (double)g4.y*b1
                   + (double)g4.z*b2 + (double)g4.w*b3;
        }
        if (kg < 15) { b0 = n0d; b1 = n1d; b2 = n2d; b3 = n3d; }
      }
      __syncthreads();                      // done reading sgf; reuse smem
      double* red = smem;                   // [3][64][17]
      if (wv > 0) {
        double* rp = red + ((size_t)(wv-1)*64 + lane)*17;
        #pragma unroll
        for (int j = 0; j < 16; ++j) rp[j] = acc[j];
      }
      __syncthreads();
      if (wv == 0) {
        #pragma unroll
        for (int w = 0; w < 3; ++w) {
          const double* rp = red + ((size_t)w*64 + lane)*17;
          #pragma unroll
          for (int j = 0; j < 16; ++j) acc[j] += rp[j];
        }
        double* pp = part + ((size_t)kc*NNODE + n0)*ECH + lane;
        #pragma unroll
        for (int jn = 0; jn < 16; ++jn)
          AT_STORED(pp + (size_t)jn*ECH, acc[jn]);
      }
    }
    grid_sync(bar, gen, bid); ++gen;

    // ---- phase CELL: 64 nc(8 nodes) x 16 rc(8 r) ----
    {
      double (*xh)[258] = (double(*)[258])smem;          // 8*258 = 2064 dbl
      double (*gbuf)[9] = (double(*)[9])(smem + 2064);   // 32*9 = 288 dbl
      const int nc = bid >> 4;
      const int rc = bid & 15;
      const int m0 = nc << 3;
      {
        const int e = tid & 63;
        #pragma unroll
        for (int pass = 0; pass < 2; ++pass) {
          const int n = (tid >> 6) + (pass << 2);
          const int m = m0 + n;
          double te = (double)b_tensor[e];
          for (int kb8 = 0; kb8 < 4; ++kb8) {
            double tv[8];
            #pragma unroll
            for (int j = 0; j < 8; ++j)
              tv[j] = AT_LOADD(part + ((size_t)((kb8<<3)+j)*NNODE + m)*ECH + e);
            #pragma unroll
            for (int j = 0; j < 8; ++j) te += tv[j];
          }
          double n0v = (double)nodes[((size_t)t*NNODE + m)*ICH + 0];
          double n1v = (double)nodes[((size_t)t*NNODE + m)*ICH + 1];
          double ie = n0v*(double)W_in[e*2] + n1v*(double)W_in[e*2+1] + (double)b_in[e];
          xh[n][e] = fmax(ie, 0.0);
          xh[n][64+e] = fmax(te, 0.0);
        }
        const int r = tid & 127;
        #pragma unroll
        for (int pass = 0; pass < 4; ++pass) {
          const int n = (tid >> 7) + (pass << 1);
          xh[n][128+r] = AT_LOADD(hcur + (size_t)(m0+n)*RCH + r);
        }
      }
      __syncthreads();
      {
        const int n = tid >> 5, tg = tid & 31;
        const int q0 = tg >> 3, jr = tg & 7;
        const int gc0 = q0*128 + rc*8 + jr;
        const double* w0 = Wcat + (size_t)gc0*256;
        double a0 = 0.0;
        #pragma unroll 8
        for (int kk = 0; kk < 256; kk += 2) {
          double2 xv = *(const double2*)(&xh[n][kk]);
          double2 wa = *(const double2*)(w0 + kk);
          a0 += xv.x*wa.x + xv.y*wa.y;
        }
        gbuf[tg][n] = a0 + bs[gc0];
      }
      __syncthreads();
      if (tid < 64) {
        const int n = tid >> 3, jr = tid & 7;
        const int m = m0 + n, r = rc*8 + jr;
        double ig = sigd(gbuf[jr][n]);
        double fg = sigd(gbuf[8+jr][n]);
        double gg = tanh(gbuf[16+jr][n]);
        double og = sigd(gbuf[24+jr][n]);
        double cold = c[(size_t)m*RCH + r];
        double c2 = fg*cold + ig*gg;
        double h2v = og*tanh(c2);
        c[(size_t)m*RCH + r] = c2;
        AT_STORED(hnxt + (size_t)m*RCH + r, h2v);
        if (t == TT-1) {
          hf[(size_t)m*RCH + r] = (float)h2v;
          cf[(size_t)m*RCH + r] = (float)c2;
        }
      }
    }
    grid_sync(bar, gen, bid); ++gen;

    // ---- phase HT+OUT: 64 mc(8 m) x 16 g; Ht(t+1) (skip last) + out[t] ----
    {
      double (*h2b)[130] = (double(*)[130])smem;
      const int mc = bid >> 4, g = bid & 15;
      const int m0 = mc << 3;
      const int r = tid & 127;
      #pragma unroll
      for (int pass = 0; pass < 4; ++pass) {
        const int n = (tid >> 7) + (pass << 1);
        h2b[n][r] = AT_LOADD(hnxt + (size_t)(m0+n)*RCH + r);
      }
      __syncthreads();
      if (t < TT-1) {
        const int e = tid & 63, mh = tid >> 6;
        const double* wt = WtT + (size_t)(g*128)*ECH + e;
        double acc[2] = {};
        #pragma unroll 4
        for (int rr = 0; rr < 128; ++rr) {
          double w0 = wt[(size_t)rr*ECH];
          acc[0] += h2b[(mh<<1)][rr]*w0;
          acc[1] += h2b[(mh<<1)+1][rr]*w0;
        }
        #pragma unroll
        for (int mi = 0; mi < 2; ++mi)
          AT_STORED(Ht + ((size_t)(m0+(mh<<1)+mi)*G2C + g)*ECH + e, acc[mi]);
      }
      if (g == 0 && tid < 40) {
        const int mi = tid / OCH, oo = tid % OCH;
        double v = (double)b_out[oo];
        #pragma unroll 8
        for (int r2 = 0; r2 < 128; ++r2)
          v += h2b[mi][r2]*(double)W_out[oo*RCH + r2];
        outp[((size_t)t*NNODE + m0 + mi)*OCH + oo] = (float)v;
      }
    }
    if (t < TT-1) { grid_sync(bar, gen, bid); ++gen; }
  }
}

extern "C" void kernel_launch(void* const* d_in, const int* in_sizes, int n_in,
                              void* d_out, int out_size, void* d_ws, size_t ws_size,
                              hipStream_t stream) {
  const float* nodes    = (const float*)d_in[0];
  const float* grids    = (const float*)d_in[1];
  const float* h0       = (const float*)d_in[2];
  const float* c0       = (const float*)d_in[3];
  const float* W_in     = (const float*)d_in[4];
  const float* b_in     = (const float*)d_in[5];
  const float* W_tensor = (const float*)d_in[6];
  const float* b_tensor = (const float*)d_in[7];
  const float* W_ih     = (const float*)d_in[8];
  const float* b_ih     = (const float*)d_in[9];
  const float* W_hh     = (const float*)d_in[10];
  const float* b_hh     = (const float*)d_in[11];
  const float* W_out    = (const float*)d_in[12];
  const float* b_out    = (const float*)d_in[13];
  double* ws = (double*)d_ws;
  float* outp = (float*)d_out;                 // [20][512][5]
  float* hf = outp + (size_t)TT*NNODE*OCH;     // [512][128]
  float* cf = hf + (size_t)NNODE*RCH;          // [512][128]

  k_init<<<256, 256, 0, stream>>>(h0, c0, W_ih, b_ih, W_hh, b_hh, W_tensor, ws);
  k_steps<<<NBLK, 256, 0, stream>>>(nodes, grids, W_in, b_in, b_tensor,
                                    W_out, b_out, ws, outp, hf, cf);
}

// Round 9
// 3383.623 us; speedup vs baseline: 1.1751x; 1.1751x over previous
//
#include <hip/hip_runtime.h>

// Problem constants
#define TT 20
#define NNODE 512
#define G2C 16
#define RCH 128
#define ECH 64
#define ICH 2
#define OCH 5
#define KSOC 8192          // N*G2
#define KSPLIT 16
#define KCH 512            // KSOC/KSPLIT
#define SGS 516            // LDS f32 row stride in k_social (conflict-free)

// workspace layout (double offsets)
#define OFF_H    0u         // h   [512*128]
#define OFF_C    65536u     // c   [512*128]
#define OFF_HT   131072u    // Ht  [8192][64]
#define OFF_PART 655360u    // part[16][512][64]
#define OFF_WCAT 1179648u   // Wcat[512 gc][256 kk] (kk<128: W_ih, kk>=128: W_hh)
#define OFF_WTT  1310720u   // WtT [2048 q2][64 e]  q2 = g*128+r
#define OFF_BS   1441792u   // bs  [512 gc]
// total 1442304 doubles = 11.54 MB

__device__ __forceinline__ double sigd(double x){ return 1.0/(1.0+exp(-x)); }

__global__ void k_init(const float* __restrict__ h0, const float* __restrict__ c0,
                       const float* __restrict__ W_ih, const float* __restrict__ b_ih,
                       const float* __restrict__ W_hh, const float* __restrict__ b_hh,
                       const float* __restrict__ W_tensor, double* __restrict__ ws) {
  int tid = blockIdx.x*blockDim.x + threadIdx.x;
  int nthr = gridDim.x*blockDim.x;
  double* h = ws + OFF_H; double* c = ws + OFF_C;
  double* Wcat = ws + OFF_WCAT; double* WtT = ws + OFF_WTT;
  double* bs = ws + OFF_BS;
  for (int i = tid; i < NNODE*RCH; i += nthr) { h[i] = (double)h0[i]; c[i] = (double)c0[i]; }
  // Wcat[gc][kk]: kk<128 -> W_ih[gc][kk]; kk>=128 -> W_hh[gc][kk-128]
  for (int i = tid; i < 512*256; i += nthr) {
    int kk = i & 255; int gc = i >> 8;
    Wcat[i] = (kk < 128) ? (double)W_ih[gc*128 + kk] : (double)W_hh[gc*128 + (kk-128)];
  }
  // WtT[q2][e] = W_tensor[e][q2],  q2 = g*128+r
  for (int i = tid; i < 2048*64; i += nthr) {
    int e = i & 63; int q2 = i >> 6;
    WtT[i] = (double)W_tensor[e*2048 + q2];
  }
  for (int i = tid; i < 512; i += nthr) bs[i] = (double)b_ih[i] + (double)b_hh[i];
}

// Ht(0): 256 blocks = 32 m-chunks(16 m) x 8 g-chunks(2 g)  (R3's k_ht_out, wout=0)
__global__ __launch_bounds__(256) void k_ht0(double* __restrict__ ws) {
  __shared__ double h2b[16][130];
  const double* __restrict__ h = ws + OFF_H;
  const double* __restrict__ WtT = ws + OFF_WTT;
  double* __restrict__ Ht = ws + OFF_HT;
  const int tid = threadIdx.x;
  const int mc = blockIdx.x >> 3;
  const int gc2 = blockIdx.x & 7;
  const int m0 = mc << 4, g0 = gc2 << 1;
  {
    const int r = tid & 127;
    #pragma unroll
    for (int pass = 0; pass < 8; ++pass) {
      const int n = (tid >> 7) + (pass << 1);
      h2b[n][r] = h[(size_t)(m0+n)*RCH + r];
    }
  }
  __syncthreads();
  const int e = tid & 63, mh = tid >> 6;
  const double* wt0 = WtT + (size_t)(g0*128)*ECH + e;
  const double* wt1 = WtT + (size_t)((g0+1)*128)*ECH + e;
  double acc[4][2] = {};
  #pragma unroll 4
  for (int rr = 0; rr < 128; ++rr) {
    double w0 = wt0[(size_t)rr*ECH];
    double w1 = wt1[(size_t)rr*ECH];
    #pragma unroll
    for (int mi = 0; mi < 4; ++mi) {
      double hv = h2b[(mh<<2)+mi][rr];
      acc[mi][0] += hv*w0;
      acc[mi][1] += hv*w1;
    }
  }
  #pragma unroll
  for (int mi = 0; mi < 4; ++mi) {
    const int m = m0 + (mh<<2) + mi;
    Ht[((size_t)m*G2C + g0    )*ECH + e] = acc[mi][0];
    Ht[((size_t)m*G2C + g0 + 1)*ECH + e] = acc[mi][1];
  }
}

// part[kc][n][e] = sum_{k in chunk kc} grid_flat[n,k] * Ht[k,e]   (byte-identical to R3)
__global__ __launch_bounds__(256) void k_social(const float* __restrict__ grids,
                                                double* __restrict__ ws, int t) {
  __shared__ __align__(16) double sgd[4160];
  float* sgf = (float*)sgd;
  const double* __restrict__ Ht = ws + OFF_HT;
  double* __restrict__ part = ws + OFF_PART;
  const int kc = blockIdx.x & (KSPLIT-1);
  const int n0 = (blockIdx.x >> 4) << 4;
  const int kb = kc * KCH;
  const int tid = threadIdx.x;
  const float* gbase = grids + (size_t)t*NNODE*KSOC;
  for (int i = tid; i < 16*128; i += 256) {
    int row = i >> 7; int c4 = i & 127;
    float4 v = *(const float4*)(gbase + (size_t)(n0+row)*KSOC + kb + (c4<<2));
    *(float4*)(&sgf[row*SGS + (c4<<2)]) = v;
  }
  __syncthreads();
  const int lane = tid & 63;
  const int wv = tid >> 6;
  const int e0 = (lane & 15) << 2;
  const int nq = lane >> 4;
  double acc[4][4] = {};
  const int kl0 = wv << 7;
  const double* htp = Ht + (size_t)(kb + kl0)*ECH + e0;
  #pragma unroll 2
  for (int kk = 0; kk < 128; kk += 2) {
    double2 b0a = *(const double2*)(htp + (size_t)kk*ECH);
    double2 b0b = *(const double2*)(htp + (size_t)kk*ECH + 2);
    double2 b1a = *(const double2*)(htp + (size_t)(kk+1)*ECH);
    double2 b1b = *(const double2*)(htp + (size_t)(kk+1)*ECH + 2);
    const int kl = kl0 + kk;
    #pragma unroll
    for (int jn = 0; jn < 4; ++jn) {
      float2 av2 = *(const float2*)(&sgf[((jn<<2)+nq)*SGS + kl]);
      double a0 = (double)av2.x, a1 = (double)av2.y;
      acc[jn][0] += a0*b0a.x + a1*b1a.x;
      acc[jn][1] += a0*b0a.y + a1*b1a.y;
      acc[jn][2] += a0*b0b.x + a1*b1b.x;
      acc[jn][3] += a0*b0b.y + a1*b1b.y;
    }
  }
  __syncthreads();
  if (wv > 0) {
    double* rp = sgd + ((size_t)(wv-1)*64 + lane)*16;
    #pragma unroll
    for (int jn = 0; jn < 4; ++jn)
      #pragma unroll
      for (int je = 0; je < 4; ++je) rp[(jn<<2)+je] = acc[jn][je];
  }
  __syncthreads();
  if (wv == 0) {
    #pragma unroll
    for (int w = 0; w < 3; ++w) {
      const double* rp = sgd + ((size_t)w*64 + lane)*16;
      #pragma unroll
      for (int jn = 0; jn < 4; ++jn)
        #pragma unroll
        for (int je = 0; je < 4; ++je) acc[jn][je] += rp[(jn<<2)+je];
    }
    #pragma unroll
    for (int jn = 0; jn < 4; ++jn) {
      double* pp = part + ((size_t)kc*NNODE + n0 + (jn<<2) + nq)*ECH + e0;
      pp[0]=acc[jn][0]; pp[1]=acc[jn][1]; pp[2]=acc[jn][2]; pp[3]=acc[jn][3];
    }
  }
}

// Fused cell + Ht(t+1) + out[t]. 256 blocks x 256 threads, 2 nodes per block.
// Thread (n = tid>>7, r = tid&127) computes all 4 gates for its (node, r):
// pointwise LSTM entirely in-registers. Then the same block computes the Ht
// rows and out for its 2 nodes from h2 in LDS. All accumulation chains match
// R3's k_cell / k_ht_out verbatim (bit-identical trajectory).
__global__ __launch_bounds__(256) void k_cellht(const float* __restrict__ nodes,
    const float* __restrict__ W_in, const float* __restrict__ b_in,
    const float* __restrict__ b_tensor,
    const float* __restrict__ W_out, const float* __restrict__ b_out,
    double* __restrict__ ws, float* __restrict__ outp,
    float* __restrict__ hf, float* __restrict__ cf, int t) {
  __shared__ double xh[2][258];    // [n][kk] kk<64 ie | 64..127 te | 128..255 h
  __shared__ double h2b[2][130];
  double* __restrict__ h = ws + OFF_H;
  double* __restrict__ c = ws + OFF_C;
  double* __restrict__ Ht = ws + OFF_HT;
  const double* __restrict__ part = ws + OFF_PART;
  const double* __restrict__ Wcat = ws + OFF_WCAT;
  const double* __restrict__ WtT = ws + OFF_WTT;
  const double* __restrict__ bs = ws + OFF_BS;
  const int tid = threadIdx.x;
  const int m0 = blockIdx.x << 1;
  // B1: stage x = [ie|te] (threads 0..127) and h (all threads)
  if (tid < 128) {
    const int n = tid >> 6, e = tid & 63;
    const int m = m0 + n;
    double te = (double)b_tensor[e];
    for (int kc = 0; kc < KSPLIT; ++kc)
      te += part[((size_t)kc*NNODE + m)*ECH + e];
    double n0v = (double)nodes[((size_t)t*NNODE + m)*ICH + 0];
    double n1v = (double)nodes[((size_t)t*NNODE + m)*ICH + 1];
    double ie = n0v*(double)W_in[e*2] + n1v*(double)W_in[e*2+1] + (double)b_in[e];
    xh[n][e] = fmax(ie, 0.0);
    xh[n][64+e] = fmax(te, 0.0);
  }
  {
    const int n = tid >> 7, r = tid & 127;
    xh[n][128+r] = h[(size_t)(m0+n)*RCH + r];
  }
  __syncthreads();
  // B2: all 4 gates for (n, r), pointwise in-registers
  {
    const int n = tid >> 7, r = tid & 127;
    const int m = m0 + n;
    const double* wA = Wcat + ((size_t)(      r) << 8);
    const double* wB = Wcat + ((size_t)(128 + r) << 8);
    const double* wC = Wcat + ((size_t)(256 + r) << 8);
    const double* wD = Wcat + ((size_t)(384 + r) << 8);
    double a0 = 0.0, a1 = 0.0, a2 = 0.0, a3 = 0.0;
    #pragma unroll 8
    for (int kk = 0; kk < 256; kk += 2) {
      double2 xv = *(const double2*)(&xh[n][kk]);
      double2 wa = *(const double2*)(wA + kk);
      double2 wb = *(const double2*)(wB + kk);
      double2 wc = *(const double2*)(wC + kk);
      double2 wd = *(const double2*)(wD + kk);
      a0 += xv.x*wa.x + xv.y*wa.y;
      a1 += xv.x*wb.x + xv.y*wb.y;
      a2 += xv.x*wc.x + xv.y*wc.y;
      a3 += xv.x*wd.x + xv.y*wd.y;
    }
    double ig = sigd(a0 + bs[r]);
    double fg = sigd(a1 + bs[128+r]);
    double gg = tanh(a2 + bs[256+r]);
    double og = sigd(a3 + bs[384+r]);
    double cold = c[(size_t)m*RCH + r];
    double c2 = fg*cold + ig*gg;
    double h2v = og*tanh(c2);
    c[(size_t)m*RCH + r] = c2;
    h[(size_t)m*RCH + r] = h2v;
    h2b[n][r] = h2v;
    if (t == TT-1) {
      hf[(size_t)m*RCH + r] = (float)h2v;
      cf[(size_t)m*RCH + r] = (float)c2;
    }
  }
  __syncthreads();
  // B3: Ht(t+1) for the block's 2 nodes (skip at last t)
  if (t < TT-1) {
    const int e = tid & 63;
    const int slot = tid >> 6;           // 0..3
    const int mi = slot >> 1;            // node 0/1
    const int g8 = (slot & 1) << 3;      // g base 0/8
    #pragma unroll
    for (int j = 0; j < 8; ++j) {
      const int g = g8 + j;
      const double* wt = WtT + (size_t)(g*128)*ECH + e;
      double acc = 0.0;
      #pragma unroll 4
      for (int rr = 0; rr < 128; ++rr)
        acc += h2b[mi][rr] * wt[(size_t)rr*ECH];
      Ht[((size_t)(m0+mi)*G2C + g)*ECH + e] = acc;
    }
  }
  // B4: out[t] for the block's 2 nodes
  if (tid < 2*OCH) {
    const int mi = tid / OCH, oo = tid % OCH;
    double v = (double)b_out[oo];
    #pragma unroll 8
    for (int r2 = 0; r2 < 128; ++r2)
      v += h2b[mi][r2]*(double)W_out[oo*RCH + r2];
    outp[((size_t)t*NNODE + m0 + mi)*OCH + oo] = (float)v;
  }
}

extern "C" void kernel_launch(void* const* d_in, const int* in_sizes, int n_in,
                              void* d_out, int out_size, void* d_ws, size_t ws_size,
                              hipStream_t stream) {
  const float* nodes    = (const float*)d_in[0];
  const float* grids    = (const float*)d_in[1];
  const float* h0       = (const float*)d_in[2];
  const float* c0       = (const float*)d_in[3];
  const float* W_in     = (const float*)d_in[4];
  const float* b_in     = (const float*)d_in[5];
  const float* W_tensor = (const float*)d_in[6];
  const float* b_tensor = (const float*)d_in[7];
  const float* W_ih     = (const float*)d_in[8];
  const float* b_ih     = (const float*)d_in[9];
  const float* W_hh     = (const float*)d_in[10];
  const float* b_hh     = (const float*)d_in[11];
  const float* W_out    = (const float*)d_in[12];
  const float* b_out    = (const float*)d_in[13];
  double* ws = (double*)d_ws;
  float* outp = (float*)d_out;                 // [20][512][5]
  float* hf = outp + (size_t)TT*NNODE*OCH;     // [512][128]
  float* cf = hf + (size_t)NNODE*RCH;          // [512][128]

  k_init<<<256, 256, 0, stream>>>(h0, c0, W_ih, b_ih, W_hh, b_hh, W_tensor, ws);
  k_ht0<<<256, 256, 0, stream>>>(ws);
  for (int t = 0; t < TT; ++t) {
    k_social<<<512, 256, 0, stream>>>(grids, ws, t);
    k_cellht<<<256, 256, 0, stream>>>(nodes, W_in, b_in, b_tensor, W_out, b_out,
                                      ws, outp, hf, cf, t);
  }
}